// Round 2
// baseline (284.500 us; speedup 1.0000x reference)
//
#include <hip/hip_runtime.h>

// Depthwise 4x4 blur, stride 2, pad 1: [16,256,256,256] f32 -> [16,256,128,128].
// Separable k = f (x) f / 64, f=[1,3,3,1].
// Pure streaming, zero-LDS: one wave sweeps a 128-output-row segment of one
// (n,c) slice. Per output row: load 2 input rows (float4/lane = coalesced 1KiB
// row), horizontal filter via shfl, vertical 4-tap kept in registers (2 H-rows
// carried), store float2/lane output row. No barriers, +0.8% halo only.
// Traffic ~1.35 GB -> ~215us roofline at 6.3 TB/s.

#define W   256
#define OW  128

__global__ __launch_bounds__(256, 8)
void downsample_fir_stream(const float* __restrict__ x,
                           const float* __restrict__ kern,
                           float* __restrict__ out) {
    const int t    = threadIdx.x;
    const int lane = t & 63;
    const int wid  = blockIdx.x * 4 + (t >> 6);  // global wave id
    const int img  = wid >> 1;                   // (n*256+c) slice, 0..4095
    const int seg  = wid & 1;                    // top / bottom half

    // Separable factors from the uniform 4x4 kernel (exact: sum(k)==1).
    float fh[4], fv[4];
#pragma unroll
    for (int i = 0; i < 4; ++i) {
        fh[i] = kern[0*4 + i] + kern[1*4 + i] + kern[2*4 + i] + kern[3*4 + i];
        fv[i] = kern[i*4 + 0] + kern[i*4 + 1] + kern[i*4 + 2] + kern[i*4 + 3];
    }

    const float* xim = x   + (size_t)img * (W * W);
    float*       oim = out + (size_t)img * (OW * OW);

    const int oy0 = seg * 64;        // first output row of this segment
    const int r0  = 2 * oy0;         // first "current" input row (128*seg)

    auto hfilt = [&](float4 v) -> float2 {
        float left  = __shfl_up(v.w, 1);     // col 4i-1
        float right = __shfl_down(v.x, 1);   // col 4i+4
        if (lane == 0)  left  = 0.f;         // zero pad col -1
        if (lane == 63) right = 0.f;         // zero pad col 256
        float2 h;
        h.x = fh[0]*left + fh[1]*v.x + fh[2]*v.y + fh[3]*v.z;
        h.y = fh[0]*v.y  + fh[1]*v.z + fh[2]*v.w + fh[3]*right;
        return h;
    };

    const float4 z4 = {0.f, 0.f, 0.f, 0.f};
    const float* rowp = xim + 4 * lane;

    // Prologue: H(r0-1) (zero pad for seg 0) and H(r0).
    float4 vA = (r0 > 0) ? *(const float4*)(rowp + (size_t)(r0 - 1) * W) : z4;
    float4 vB = *(const float4*)(rowp + (size_t)r0 * W);
    float2 hA = hfilt(vA);
    float2 hB = hfilt(vB);

#pragma unroll 4
    for (int i = 0; i < 64; ++i) {
        const int r1 = r0 + 2 * i + 1;
        const int r2 = r0 + 2 * i + 2;
        const float4 v1 = *(const float4*)(rowp + (size_t)r1 * W);
        const float4 v2 = (r2 < W) ? *(const float4*)(rowp + (size_t)r2 * W) : z4;
        const float2 h1 = hfilt(v1);
        const float2 h2 = hfilt(v2);
        float2 o;
        o.x = fv[0]*hA.x + fv[1]*hB.x + fv[2]*h1.x + fv[3]*h2.x;
        o.y = fv[0]*hA.y + fv[1]*hB.y + fv[2]*h1.y + fv[3]*h2.y;
        *(float2*)(oim + (size_t)(oy0 + i) * OW + 2 * lane) = o;
        hA = h1; hB = h2;
    }
}

extern "C" void kernel_launch(void* const* d_in, const int* in_sizes, int n_in,
                              void* d_out, int out_size, void* d_ws, size_t ws_size,
                              hipStream_t stream) {
    const float* x    = (const float*)d_in[0];
    const float* kern = (const float*)d_in[1];
    float* out        = (float*)d_out;

    const int nimg  = in_sizes[0] / (W * W);  // 4096 (n,c) slices
    const int waves = nimg * 2;               // 2 segments per slice
    dim3 grid(waves / 4);                     // 4 waves per 256-thread block
    dim3 block(256);
    downsample_fir_stream<<<grid, block, 0, stream>>>(x, kern, out);
}

// Round 4
// 238.730 us; speedup vs baseline: 1.1917x; 1.1917x over previous
//
#include <hip/hip_runtime.h>

// Depthwise 4x4 blur, stride 2, pad 1: [16,256,256,256] f32 -> [16,256,128,128].
// Separable k = f (x) f / 64, f=[1,3,3,1]. Two-phase LDS-tiled (R1 structure):
//   phase 1: horizontal filter during coalesced float4 row loads (shfl halo) -> LDS
//   phase 2: vertical 4-tap from LDS, nontemporal float4 stores.
// vs R1: TOY 16->32 w/ 512-thread blocks (halo 6.25%->3.1%,
// 33.8KB LDS -> 4 blocks/CU x 8 waves = 32 waves/CU still), nt stores.

#define W    256   // input H=W
#define OW   128   // output H=W
#define TOY  32    // output rows per tile
#define IN_ROWS (2*TOY + 2)   // 66 input rows staged per tile

typedef float vfloat4 __attribute__((ext_vector_type(4)));  // native vec for nt-store

__global__ __launch_bounds__(512)
void downsample_fir_kernel(const float* __restrict__ x,
                           const float* __restrict__ kern,
                           float* __restrict__ out) {
    const int bid  = blockIdx.x;
    const int img  = bid >> 2;     // n*256 + c  (0..4095)
    const int tile = bid & 3;      // 4 row-tiles per image
    const int t    = threadIdx.x;
    const int lane = t & 63;
    const int wave = t >> 6;       // 0..7

    // Separable factors from the (uniform) 4x4 kernel (exact: sum(k)==1).
    float fh[4], fv[4];
#pragma unroll
    for (int i = 0; i < 4; ++i) {
        fh[i] = kern[0*4 + i] + kern[1*4 + i] + kern[2*4 + i] + kern[3*4 + i];
        fv[i] = kern[i*4 + 0] + kern[i*4 + 1] + kern[i*4 + 2] + kern[i*4 + 3];
    }

    // H rows: one per staged input row, 128 horizontal-filtered values each.
    __shared__ float Hlds[IN_ROWS][OW];   // 66*128*4 = 33792 B

    const float* xim = x + (size_t)img * (W * W);
    const int rowBase = tile * (2 * TOY) - 1;   // input row of LDS row 0 (pad 1)

    // ---- Phase 1: horizontal pass. One wave per input row, 8 waves stride. ----
    for (int r = wave; r < IN_ROWS; r += 8) {
        const int g = rowBase + r;          // global input row (may be -1 or 256)
        float2 h;
        if (g >= 0 && g < W) {
            const float4 v = *(const float4*)(xim + (size_t)g * W + 4 * lane);
            float left  = __shfl_up(v.w, 1);    // col 4i-1
            float right = __shfl_down(v.x, 1);  // col 4i+4
            if (lane == 0)  left  = 0.f;        // zero pad col -1
            if (lane == 63) right = 0.f;        // zero pad col 256
            h.x = fh[0]*left + fh[1]*v.x + fh[2]*v.y + fh[3]*v.z;
            h.y = fh[0]*v.y  + fh[1]*v.z + fh[2]*v.w + fh[3]*right;
        } else {
            h.x = 0.f; h.y = 0.f;               // zero-pad rows -1 / 256
        }
        *(float2*)&Hlds[r][2 * lane] = h;       // contiguous 8B/lane
    }
    __syncthreads();

    // ---- Phase 2: vertical pass. Thread -> 2 float4 outputs, nt stores. ----
    const int ox0 = (t & 31) * 4;   // output col group (0..124)
    const int g0  = t >> 5;         // 0..15
    float* oim = out + (size_t)img * (OW * OW) + (size_t)tile * TOY * OW;
#pragma unroll
    for (int s = 0; s < 2; ++s) {
        const int oyp = g0 + 16 * s;    // output row within tile, 0..31
        const int rr  = 2 * oyp;        // LDS rows rr..rr+3
        const float4 h0 = *(const float4*)&Hlds[rr + 0][ox0];
        const float4 h1 = *(const float4*)&Hlds[rr + 1][ox0];
        const float4 h2 = *(const float4*)&Hlds[rr + 2][ox0];
        const float4 h3 = *(const float4*)&Hlds[rr + 3][ox0];
        vfloat4 o;
        o.x = fv[0]*h0.x + fv[1]*h1.x + fv[2]*h2.x + fv[3]*h3.x;
        o.y = fv[0]*h0.y + fv[1]*h1.y + fv[2]*h2.y + fv[3]*h3.y;
        o.z = fv[0]*h0.z + fv[1]*h1.z + fv[2]*h2.z + fv[3]*h3.z;
        o.w = fv[0]*h0.w + fv[1]*h1.w + fv[2]*h2.w + fv[3]*h3.w;
        __builtin_nontemporal_store(o, (vfloat4*)(oim + (size_t)oyp * OW + ox0));
    }
}

extern "C" void kernel_launch(void* const* d_in, const int* in_sizes, int n_in,
                              void* d_out, int out_size, void* d_ws, size_t ws_size,
                              hipStream_t stream) {
    const float* x    = (const float*)d_in[0];
    const float* kern = (const float*)d_in[1];
    float* out        = (float*)d_out;

    const int nimg = in_sizes[0] / (W * W);   // 16*256 = 4096 (n,c) slices
    dim3 grid(nimg * 4);                      // 4 row-tiles per slice
    dim3 block(512);
    downsample_fir_kernel<<<grid, block, 0, stream>>>(x, kern, out);
}

// Round 5
// 235.888 us; speedup vs baseline: 1.2061x; 1.0120x over previous
//
#include <hip/hip_runtime.h>

// Depthwise 4x4 blur, stride 2, pad 1: [16,256,256,256] f32 -> [16,256,128,128].
// Separable k = f (x) f / 64, f=[1,3,3,1]. Two-phase LDS-tiled:
//   phase 1: horizontal filter during coalesced float4 row loads (shfl halo) -> LDS
//   phase 2: vertical 4-tap from LDS, nontemporal float4 stores.
// R5 change: XCD-aware blockIdx swizzle — all 4 tiles of one image map to the
// same XCD and are co-resident, so the 2 shared halo rows between adjacent
// tiles hit that XCD's L2 (instead of LLC/HBM). 16384 blocks % 8 XCDs == 0,
// mapping is bijective.

#define W    256   // input H=W
#define OW   128   // output H=W
#define TOY  32    // output rows per tile
#define IN_ROWS (2*TOY + 2)   // 66 input rows staged per tile
#define NXCD 8

typedef float vfloat4 __attribute__((ext_vector_type(4)));  // native vec for nt-store

__global__ __launch_bounds__(512)
void downsample_fir_kernel(const float* __restrict__ x,
                           const float* __restrict__ kern,
                           float* __restrict__ out) {
    // ---- XCD swizzle: hardware assigns XCD = blockIdx.x % 8 (round-robin).
    // Give XCD x the images {i : i%8 == x}; within an XCD, consecutive slots
    // enumerate (image-group, tile) so all 4 tiles of an image are adjacent.
    const int bid  = blockIdx.x;
    const int xcd  = bid & 7;          // this block's XCD
    const int slot = bid >> 3;         // 0..2047 within XCD
    const int img  = (slot >> 2) * NXCD + xcd;   // n*256 + c  (0..4095)
    const int tile = slot & 3;                   // 4 row-tiles per image
    const int t    = threadIdx.x;
    const int lane = t & 63;
    const int wave = t >> 6;       // 0..7

    // Separable factors from the (uniform) 4x4 kernel (exact: sum(k)==1).
    float fh[4], fv[4];
#pragma unroll
    for (int i = 0; i < 4; ++i) {
        fh[i] = kern[0*4 + i] + kern[1*4 + i] + kern[2*4 + i] + kern[3*4 + i];
        fv[i] = kern[i*4 + 0] + kern[i*4 + 1] + kern[i*4 + 2] + kern[i*4 + 3];
    }

    // H rows: one per staged input row, 128 horizontal-filtered values each.
    __shared__ float Hlds[IN_ROWS][OW];   // 66*128*4 = 33792 B

    const float* xim = x + (size_t)img * (W * W);
    const int rowBase = tile * (2 * TOY) - 1;   // input row of LDS row 0 (pad 1)

    // ---- Phase 1: horizontal pass. One wave per input row, 8 waves stride. ----
    for (int r = wave; r < IN_ROWS; r += 8) {
        const int g = rowBase + r;          // global input row (may be -1 or 256)
        float2 h;
        if (g >= 0 && g < W) {
            const float4 v = *(const float4*)(xim + (size_t)g * W + 4 * lane);
            float left  = __shfl_up(v.w, 1);    // col 4i-1
            float right = __shfl_down(v.x, 1);  // col 4i+4
            if (lane == 0)  left  = 0.f;        // zero pad col -1
            if (lane == 63) right = 0.f;        // zero pad col 256
            h.x = fh[0]*left + fh[1]*v.x + fh[2]*v.y + fh[3]*v.z;
            h.y = fh[0]*v.y  + fh[1]*v.z + fh[2]*v.w + fh[3]*right;
        } else {
            h.x = 0.f; h.y = 0.f;               // zero-pad rows -1 / 256
        }
        *(float2*)&Hlds[r][2 * lane] = h;       // contiguous 8B/lane
    }
    __syncthreads();

    // ---- Phase 2: vertical pass. Thread -> 2 float4 outputs, nt stores. ----
    const int ox0 = (t & 31) * 4;   // output col group (0..124)
    const int g0  = t >> 5;         // 0..15
    float* oim = out + (size_t)img * (OW * OW) + (size_t)tile * TOY * OW;
#pragma unroll
    for (int s = 0; s < 2; ++s) {
        const int oyp = g0 + 16 * s;    // output row within tile, 0..31
        const int rr  = 2 * oyp;        // LDS rows rr..rr+3
        const float4 h0 = *(const float4*)&Hlds[rr + 0][ox0];
        const float4 h1 = *(const float4*)&Hlds[rr + 1][ox0];
        const float4 h2 = *(const float4*)&Hlds[rr + 2][ox0];
        const float4 h3 = *(const float4*)&Hlds[rr + 3][ox0];
        vfloat4 o;
        o.x = fv[0]*h0.x + fv[1]*h1.x + fv[2]*h2.x + fv[3]*h3.x;
        o.y = fv[0]*h0.y + fv[1]*h1.y + fv[2]*h2.y + fv[3]*h3.y;
        o.z = fv[0]*h0.z + fv[1]*h1.z + fv[2]*h2.z + fv[3]*h3.z;
        o.w = fv[0]*h0.w + fv[1]*h1.w + fv[2]*h2.w + fv[3]*h3.w;
        __builtin_nontemporal_store(o, (vfloat4*)(oim + (size_t)oyp * OW + ox0));
    }
}

extern "C" void kernel_launch(void* const* d_in, const int* in_sizes, int n_in,
                              void* d_out, int out_size, void* d_ws, size_t ws_size,
                              hipStream_t stream) {
    const float* x    = (const float*)d_in[0];
    const float* kern = (const float*)d_in[1];
    float* out        = (float*)d_out;

    const int nimg = in_sizes[0] / (W * W);   // 16*256 = 4096 (n,c) slices
    dim3 grid(nimg * 4);                      // 4 row-tiles per slice
    dim3 block(512);
    downsample_fir_kernel<<<grid, block, 0, stream>>>(x, kern, out);
}